// Round 1
// baseline (71.623 us; speedup 1.0000x reference)
//
#include <hip/hip_runtime.h>

// KVEmbedding gather: out[b,l,:] = table[indices[b,l], :]
// indices: int32 [4096*200], table: float32 [1'000'000 x 64], out: float32 [4096*200*64]
// 16 threads cooperate on one 64-float row; each thread moves one float4 (16 B).

__global__ __launch_bounds__(256) void kv_gather_kernel(
    const int* __restrict__ idx,
    const float* __restrict__ table,
    float* __restrict__ out,
    long long nrows)
{
    const long long total = nrows << 4;  // 16 float4 chunks per row
    long long i = (long long)blockIdx.x * blockDim.x + threadIdx.x;
    const long long stride = (long long)gridDim.x * blockDim.x;
    for (; i < total; i += stride) {
        const long long row = i >> 4;
        const int sub = (int)(i & 15);
        const long long t = (long long)idx[row];
        const float4* __restrict__ src =
            reinterpret_cast<const float4*>(table + t * 64);
        float4* __restrict__ dst =
            reinterpret_cast<float4*>(out + row * 64);
        dst[sub] = src[sub];
    }
}

extern "C" void kernel_launch(void* const* d_in, const int* in_sizes, int n_in,
                              void* d_out, int out_size, void* d_ws, size_t ws_size,
                              hipStream_t stream)
{
    const int*   idx   = (const int*)d_in[0];    // indices [4096*200]
    const float* table = (const float*)d_in[1];  // table [1e6 * 64]
    float*       out   = (float*)d_out;          // [4096*200*64]

    const long long nrows = in_sizes[0];          // 819200
    const long long total = nrows << 4;           // float4 chunks

    const int block = 256;
    long long nblk = (total + block - 1) / block;
    const long long maxblk = 256LL * 8;           // 8 blocks/CU, grid-stride the rest
    if (nblk > maxblk) nblk = maxblk;

    kv_gather_kernel<<<(int)nblk, block, 0, stream>>>(idx, table, out, nrows);
}